// Round 6
// baseline (1331.301 us; speedup 1.0000x reference)
//
#include <hip/hip_runtime.h>
#include <hip/hip_bf16.h>
#include <math.h>

// Problem constants
#define Bsz 256
#define Hh 26
#define Ww 26
#define Ll 624
#define DDc 128
#define CHc 256
#define NLl 4
#define NPIX (Hh * Ww)            // 676
#define NROWS (Bsz * NPIX)        // 173056
#define GRID_ELEMS (NROWS * DDc)  // 22151168

typedef short short8v __attribute__((ext_vector_type(8)));   // 8 bf16 (4 VGPRs)
typedef float f32x4 __attribute__((ext_vector_type(4)));
typedef unsigned short ushort4v __attribute__((ext_vector_type(4)));

__device__ __forceinline__ unsigned short f2bf(float f) {
    union { float f; unsigned int u; } v; v.f = f;
    unsigned int u = v.u;
    return (unsigned short)((u + 0x7FFFu + ((u >> 16) & 1u)) >> 16);   // RNE
}

// Branchless gelu via Abramowitz-Stegun 7.1.26 erf (|err| < 1.5e-7)
__device__ __forceinline__ float fast_gelu(float x) {
    float z = x * 0.70710678118654752f;
    float a = fabsf(z);
    float t = 1.0f / fmaf(0.3275911f, a, 1.0f);
    float p = fmaf(1.061405429f, t, -1.453152027f);
    p = fmaf(p, t, 1.421413741f);
    p = fmaf(p, t, -0.284496736f);
    p = fmaf(p, t, 0.254829592f);
    float e = __expf(-a * a);
    float y = fmaf(-p * t, e, 1.0f);
    float er = copysignf(y, z);
    return 0.5f * x * (1.0f + er);
}

// ---------------------------------------------------------------------------
__global__ void build_inv_kernel(const int* __restrict__ coords, int* __restrict__ inv) {
    int i = threadIdx.x;
    if (i < NPIX) inv[i] = -1;
    __syncthreads();
    if (i < Ll) {
        int r = coords[2 * i + 0];
        int c = coords[2 * i + 1];
        inv[r * Ww + c] = i;
    }
}

// ---------------------------------------------------------------------------
__global__ __launch_bounds__(256) void scatter_kernel(const float* __restrict__ X,
                                                      const float* __restrict__ P,
                                                      const int* __restrict__ inv,
                                                      float* __restrict__ Y) {
    int idx = blockIdx.x * blockDim.x + threadIdx.x;
    int r = idx >> 5;
    int c4 = idx & 31;
    int b = r / NPIX;
    int pos = r - b * NPIX;
    int li = inv[pos];
    float4 v;
    if (li >= 0) v = *(const float4*)(X + ((size_t)(b * Ll + li) * DDc + c4 * 4));
    else         v = *(const float4*)(P + c4 * 4);
    *(float4*)(Y + ((size_t)r * DDc + c4 * 4)) = v;
}

// ---------------------------------------------------------------------------
__global__ __launch_bounds__(256) void wprep_kernel(const float* __restrict__ in,
                                                    unsigned short* __restrict__ out,
                                                    int R, int C) {
    __shared__ float t[32][33];
    int bz = blockIdx.z;
    const float* ip = in + (size_t)bz * R * C;
    unsigned short* op = out + (size_t)bz * R * C;
    int c0 = blockIdx.x * 32, r0 = blockIdx.y * 32;
    int tx = threadIdx.x & 31, ty = threadIdx.x >> 5;   // 32 x 8
#pragma unroll
    for (int i = 0; i < 32; i += 8)
        t[ty + i][tx] = ip[(size_t)(r0 + ty + i) * C + c0 + tx];
    __syncthreads();
#pragma unroll
    for (int i = 0; i < 32; i += 8)
        op[(size_t)(c0 + ty + i) * R + r0 + tx] = f2bf(t[tx][ty + i]);
}

// ---------------------------------------------------------------------------
__global__ __launch_bounds__(256) void ln_kernel(const float* __restrict__ Y,
                                                 const float* __restrict__ scale,
                                                 const float* __restrict__ bias,
                                                 unsigned short* __restrict__ Yn) {
    int wave = threadIdx.x >> 6;
    int lane = threadIdx.x & 63;
    int r = blockIdx.x * 4 + wave;
    const float* yr = Y + (size_t)r * DDc;
    float2 v = *(const float2*)(yr + lane * 2);
    float s = v.x + v.y;
#pragma unroll
    for (int off = 32; off >= 1; off >>= 1) s += __shfl_xor(s, off, 64);
    float mean = s * (1.0f / 128.0f);
    float dx = v.x - mean, dy = v.y - mean;
    float s2 = dx * dx + dy * dy;
#pragma unroll
    for (int off = 32; off >= 1; off >>= 1) s2 += __shfl_xor(s2, off, 64);
    float rstd = rsqrtf(s2 * (1.0f / 128.0f) + 1e-5f);
    float2 sc = *(const float2*)(scale + lane * 2);
    float2 bi = *(const float2*)(bias + lane * 2);
    ushort2 o;
    o.x = f2bf(dx * rstd * sc.x + bi.x);
    o.y = f2bf(dy * rstd * sc.y + bi.y);
    *(ushort2*)(Yn + (size_t)r * DDc + lane * 2) = o;
}

// ---------------------------------------------------------------------------
// Fused MFMA layer kernel. Block = (b, row-pair), 256 threads = 4 waves.
// LDS: A-slab (28672 B) ALIASED with H (32768 B), + 256 B zero pad.
// Conv MFMAs operand-SWAPPED: acc = mfma(Wfrag, Actfrag).
// Per ks-step: [issue next-step 4 global B-frags + 4 LDS A-frags]
//              sched_barrier(0)   <- pins loads ABOVE the MFMA cluster so the
//                                    scheduler cannot sink them to use-site
//              [16 MFMAs on current regs]  (auto-waitcnt stays counted:
//                                           no barrier inside this loop)
#define Z_OFF 32768
#define LDS_TOTAL 33024

__global__ __launch_bounds__(256, 3) void conv_mfma_kernel(
    const unsigned short* __restrict__ Yn,
    const unsigned short* __restrict__ w3bt,   // [9][256 n][128 k] bf16
    const float* __restrict__ b3l,
    const unsigned short* __restrict__ w1bt,   // [128 d][256 n] bf16
    const float* __restrict__ b1l,
    float* __restrict__ Y) {
    __shared__ __align__(16) char lds[LDS_TOTAL];

    int bx = blockIdx.x;
    int b = bx / 13;
    int h0 = (bx - b * 13) * 2;
    int tid = threadIdx.x;
    int lane = tid & 63, wv = tid >> 6;
    int al = lane & 15, ah = lane >> 4;

    // ---- stage A: rows h0-1..h0+2, cols -1..26, 128ch bf16, XOR-swizzled rows
    for (int i = tid; i < 4 * 28 * 16; i += 256) {     // 16B chunks
        int row4 = i / (28 * 16);
        int rem = i - row4 * (28 * 16);
        int col = rem >> 4;
        int c8 = (rem & 15) << 3;
        int hs = h0 - 1 + row4;
        int ws = col - 1;
        uint4 v = make_uint4(0u, 0u, 0u, 0u);
        if (hs >= 0 && hs < Hh && ws >= 0 && ws < Ww)
            v = *(const uint4*)(Yn + (((size_t)(b * Hh + hs) * Ww + ws) << 7) + c8);
        int r = row4 * 28 + col;
        unsigned int addr = (unsigned int)(r * 256 + c8 * 2);
        addr ^= (unsigned int)((r & 7) << 4);
        *(uint4*)(lds + addr) = v;
    }
    if (tid < 16) *(uint4*)(lds + Z_OFF + tid * 16) = make_uint4(0u, 0u, 0u, 0u);
    __syncthreads();

    // ---- per-lane M decomposition (m = mt*16 + al)
    int r00[4]; bool mpad[4];
#pragma unroll
    for (int mt = 0; mt < 4; ++mt) {
        int m = mt * 16 + al;
        bool pad = (m >= 52);
        int rh = (m >= 26) ? 1 : 0;
        int w = m - rh * 26;
        if (pad) { rh = 1; w = 0; }
        mpad[mt] = pad;
        r00[mt] = rh * 28 + w;
    }

    // ---- conv 3x3 via swapped MFMA, software-pipelined depth 1 (pinned)
    f32x4 acc[4][4];
#pragma unroll
    for (int mt = 0; mt < 4; ++mt)
#pragma unroll
        for (int nt = 0; nt < 4; ++nt) acc[mt][nt] = (f32x4)0.0f;

    int nw0 = wv * 64;
    const unsigned short* pB = w3bt + ((size_t)(nw0 + al) << 7) + ah * 8;
    const unsigned short* pBt = pB;

    unsigned int ah16 = (unsigned int)(ah * 16);
    unsigned int abase[4];
#pragma unroll
    for (int mt = 0; mt < 4; ++mt) {
        int row = r00[mt];                        // tap 0: dh=0,dw=0
        unsigned int sw = (unsigned int)((row & 7) << 4);
        abase[mt] = mpad[mt] ? (unsigned int)(Z_OFF) + ah16
                             : ((unsigned int)(row << 8) + (ah16 ^ sw));
    }

    short8v bc[4], afc[4];
#pragma unroll
    for (int nt = 0; nt < 4; ++nt) bc[nt] = *(const short8v*)(pBt + nt * 2048);
#pragma unroll
    for (int mt = 0; mt < 4; ++mt) afc[mt] = *(const short8v*)(lds + abase[mt]);

    int dh = 0, dw = 0;
#pragma unroll 1
    for (int tap = 0; tap < 9; ++tap) {
        // next tap's A row bases
        int dwn = dw + 1, dhn = dh;
        if (dwn == 3) { dwn = 0; dhn += 1; }
        unsigned int abasen[4];
#pragma unroll
        for (int mt = 0; mt < 4; ++mt) {
            int row = r00[mt] + dhn * 28 + dwn;
            if (row > 111) row = 111;             // tap==8 dummy prefetch clamp
            unsigned int sw = (unsigned int)((row & 7) << 4);
            abasen[mt] = mpad[mt] ? (unsigned int)(Z_OFF) + ah16
                                  : ((unsigned int)(row << 8) + (ah16 ^ sw));
        }
#pragma unroll
        for (int ks = 0; ks < 4; ++ks) {
            short8v bn[4], afn[4];
            const unsigned short* pn = (ks < 3) ? (pBt + (ks + 1) * 32) : (pBt + 32768);
#pragma unroll
            for (int nt = 0; nt < 4; ++nt) bn[nt] = *(const short8v*)(pn + nt * 2048);
#pragma unroll
            for (int mt = 0; mt < 4; ++mt) {
                unsigned int a = (ks < 3) ? (abase[mt] ^ (unsigned int)((ks + 1) << 6))
                                          : abasen[mt];
                afn[mt] = *(const short8v*)(lds + a);
            }
            // Pin: next-step loads must issue BEFORE this step's MFMA cluster.
            __builtin_amdgcn_sched_barrier(0);
#pragma unroll
            for (int mt = 0; mt < 4; ++mt)
#pragma unroll
                for (int nt = 0; nt < 4; ++nt)
                    acc[mt][nt] = __builtin_amdgcn_mfma_f32_16x16x32_bf16(
                        bc[nt], afc[mt], acc[mt][nt], 0, 0, 0);
#pragma unroll
            for (int nt = 0; nt < 4; ++nt) bc[nt] = bn[nt];
#pragma unroll
            for (int mt = 0; mt < 4; ++mt) afc[mt] = afn[mt];
        }
#pragma unroll
        for (int mt = 0; mt < 4; ++mt) abase[mt] = abasen[mt];
        pBt += 32768;
        dw = dwn; dh = dhn;
    }
    __syncthreads();   // all A-reads done; H region may now overwrite A region

    // ---- bias + gelu -> H [64 m][256 n] bf16, packed b64 writes
    unsigned int hswz = ((unsigned int)(al & 7)) << 4;   // m&7 == al&7
#pragma unroll
    for (int nt = 0; nt < 4; ++nt) {
        int n0 = nw0 + nt * 16 + ah * 4;
        float4 bv = *(const float4*)(b3l + n0);
#pragma unroll
        for (int mt = 0; mt < 4; ++mt) {
            int m = mt * 16 + al;
            ushort4v o;
            o[0] = f2bf(fast_gelu(acc[mt][nt][0] + bv.x));
            o[1] = f2bf(fast_gelu(acc[mt][nt][1] + bv.y));
            o[2] = f2bf(fast_gelu(acc[mt][nt][2] + bv.z));
            o[3] = f2bf(fast_gelu(acc[mt][nt][3] + bv.w));
            unsigned int addr = ((unsigned int)(m * 512 + n0 * 2)) ^ hswz;
            *(ushort4v*)(lds + addr) = o;
        }
    }
    __syncthreads();

    // ---- 1x1 via MFMA: [64 x 256] @ [256 -> 128]
    f32x4 acc1[4][2];
#pragma unroll
    for (int mt = 0; mt < 4; ++mt) { acc1[mt][0] = (f32x4)0.0f; acc1[mt][1] = (f32x4)0.0f; }
    int nw1 = wv * 32;
    const unsigned short* pW1 = w1bt + ((size_t)(nw1 + al) << 8) + ah * 8;

#pragma unroll
    for (int ks = 0; ks < 8; ++ks) {
        short8v hf[4], wf[2];
#pragma unroll
        for (int mt = 0; mt < 4; ++mt) {
            unsigned int a = ((unsigned int)((mt * 16 + al) * 512 + ks * 64 + ah * 16)) ^ hswz;
            hf[mt] = *(const short8v*)(lds + a);
        }
        wf[0] = *(const short8v*)(pW1 + ks * 32);
        wf[1] = *(const short8v*)(pW1 + 4096 + ks * 32);
#pragma unroll
        for (int mt = 0; mt < 4; ++mt)
#pragma unroll
            for (int ntl = 0; ntl < 2; ++ntl)
                acc1[mt][ntl] = __builtin_amdgcn_mfma_f32_16x16x32_bf16(
                    hf[mt], wf[ntl], acc1[mt][ntl], 0, 0, 0);
    }

    // ---- bias + residual into Y (fp32)
#pragma unroll
    for (int ntl = 0; ntl < 2; ++ntl) {
        int n = nw1 + ntl * 16 + al;
        float bias = b1l[n];
#pragma unroll
        for (int mt = 0; mt < 4; ++mt) {
#pragma unroll
            for (int j = 0; j < 4; ++j) {
                int m = mt * 16 + ah * 4 + j;
                if (m < 52) {
                    int rh = (m >= 26) ? 1 : 0;
                    int w = m - rh * 26;
                    float* yp = Y + (((size_t)(b * Hh + h0 + rh) * Ww + w) << 7) + n;
                    *yp += acc1[mt][ntl][j] + bias;
                }
            }
        }
    }
}

// ---------------------------------------------------------------------------
__global__ __launch_bounds__(256) void gather_kernel(const float* __restrict__ Y,
                                                     const int* __restrict__ coords,
                                                     float* __restrict__ Z) {
    int idx = blockIdx.x * blockDim.x + threadIdx.x;
    int r = idx >> 5;
    int c4 = idx & 31;
    int b = r / Ll;
    int li = r - b * Ll;
    int row = coords[2 * li + 0];
    int col = coords[2 * li + 1];
    float4 v = *(const float4*)(Y + (((size_t)(b * NPIX + row * Ww + col)) * DDc + c4 * 4));
    *(float4*)(Z + ((size_t)r * DDc + c4 * 4)) = v;
}

// ---------------------------------------------------------------------------
extern "C" void kernel_launch(void* const* d_in, const int* in_sizes, int n_in,
                              void* d_out, int out_size, void* d_ws, size_t ws_size,
                              hipStream_t stream) {
    const float* X = (const float*)d_in[0];
    const int* coords = (const int*)d_in[1];
    const float* P = (const float*)d_in[2];
    const float* ln_scale = (const float*)d_in[3];
    const float* ln_bias = (const float*)d_in[4];
    const float* w3 = (const float*)d_in[5];
    const float* b3 = (const float*)d_in[6];
    const float* w1 = (const float*)d_in[7];
    const float* b1 = (const float*)d_in[8];

    float* Y = (float*)d_ws;
    unsigned short* Yn = (unsigned short*)(Y + GRID_ELEMS);
    unsigned short* w3bt = Yn + GRID_ELEMS;
    unsigned short* w1bt = w3bt + (size_t)NLl * 9 * CHc * DDc;
    int* inv = (int*)(w1bt + (size_t)NLl * DDc * CHc);

    build_inv_kernel<<<1, 1024, 0, stream>>>(coords, inv);

    wprep_kernel<<<dim3(CHc / 32, DDc / 32, NLl * 9), 256, 0, stream>>>(w3, w3bt, DDc, CHc);
    wprep_kernel<<<dim3(DDc / 32, CHc / 32, NLl), 256, 0, stream>>>(w1, w1bt, CHc, DDc);

    scatter_kernel<<<(NROWS * 32) / 256, 256, 0, stream>>>(X, P, inv, Y);

    for (int l = 0; l < NLl; ++l) {
        ln_kernel<<<NROWS / 4, 256, 0, stream>>>(Y, ln_scale + l * DDc, ln_bias + l * DDc, Yn);
        conv_mfma_kernel<<<Bsz * 13, 256, 0, stream>>>(
            Yn,
            w3bt + (size_t)l * 9 * CHc * DDc,
            b3 + (size_t)l * CHc,
            w1bt + (size_t)l * DDc * CHc,
            b1 + (size_t)l * DDc,
            Y);
    }

    gather_kernel<<<(Bsz * Ll * 32) / 256, 256, 0, stream>>>(Y, coords, (float*)d_out);
}

// Round 7
// 906.600 us; speedup vs baseline: 1.4685x; 1.4685x over previous
//
#include <hip/hip_runtime.h>
#include <hip/hip_bf16.h>
#include <math.h>

// Problem constants
#define Bsz 256
#define Hh 26
#define Ww 26
#define Ll 624
#define DDc 128
#define CHc 256
#define NLl 4
#define NPIX (Hh * Ww)            // 676
#define NROWS (Bsz * NPIX)        // 173056
#define GRID_ELEMS (NROWS * DDc)  // 22151168

typedef short short8v __attribute__((ext_vector_type(8)));   // 8 bf16 (4 VGPRs)
typedef float f32x4 __attribute__((ext_vector_type(4)));
typedef unsigned short ushort4v __attribute__((ext_vector_type(4)));

__device__ __forceinline__ unsigned short f2bf(float f) {
    union { float f; unsigned int u; } v; v.f = f;
    unsigned int u = v.u;
    return (unsigned short)((u + 0x7FFFu + ((u >> 16) & 1u)) >> 16);   // RNE
}

// Branchless gelu via Abramowitz-Stegun 7.1.26 erf (|err| < 1.5e-7)
__device__ __forceinline__ float fast_gelu(float x) {
    float z = x * 0.70710678118654752f;
    float a = fabsf(z);
    float t = 1.0f / fmaf(0.3275911f, a, 1.0f);
    float p = fmaf(1.061405429f, t, -1.453152027f);
    p = fmaf(p, t, 1.421413741f);
    p = fmaf(p, t, -0.284496736f);
    p = fmaf(p, t, 0.254829592f);
    float e = __expf(-a * a);
    float y = fmaf(-p * t, e, 1.0f);
    float er = copysignf(y, z);
    return 0.5f * x * (1.0f + er);
}

// ---------------------------------------------------------------------------
__global__ void build_inv_kernel(const int* __restrict__ coords, int* __restrict__ inv) {
    int i = threadIdx.x;
    if (i < NPIX) inv[i] = -1;
    __syncthreads();
    if (i < Ll) {
        int r = coords[2 * i + 0];
        int c = coords[2 * i + 1];
        inv[r * Ww + c] = i;
    }
}

// ---------------------------------------------------------------------------
__global__ __launch_bounds__(256) void scatter_kernel(const float* __restrict__ X,
                                                      const float* __restrict__ P,
                                                      const int* __restrict__ inv,
                                                      float* __restrict__ Y) {
    int idx = blockIdx.x * blockDim.x + threadIdx.x;
    int r = idx >> 5;
    int c4 = idx & 31;
    int b = r / NPIX;
    int pos = r - b * NPIX;
    int li = inv[pos];
    float4 v;
    if (li >= 0) v = *(const float4*)(X + ((size_t)(b * Ll + li) * DDc + c4 * 4));
    else         v = *(const float4*)(P + c4 * 4);
    *(float4*)(Y + ((size_t)r * DDc + c4 * 4)) = v;
}

// ---------------------------------------------------------------------------
// Pack w3 into MFMA-fragment order:
//   w3f chunk index g = ((l*9 + tap)*16 + nt)*4 + ks ; within chunk:
//   [lane(64)][8 bf16], lane = ah*16 + al : n = nt*16+al, k = ks*32+ah*8+e.
// A wave's B-frag load becomes base + lane*16B -> contiguous 1KB.
__global__ __launch_bounds__(256) void pack3_kernel(const float* __restrict__ w3,
                                                    unsigned short* __restrict__ w3f) {
    int g = blockIdx.x * 4 + (threadIdx.x >> 6);
    int lane = threadIdx.x & 63;
    int ks = g & 3;
    int nt = (g >> 2) & 15;
    int lt = g >> 6;          // l*9 + tap
    int al = lane & 15, ah = lane >> 4;
    int n = nt * 16 + al;
    int k0 = ks * 32 + ah * 8;
    const float* src = w3 + ((size_t)lt * 128 + k0) * 256 + n;
    unsigned short* dst = w3f + ((size_t)g * 64 + lane) * 8;
#pragma unroll
    for (int e = 0; e < 8; ++e)
        dst[e] = f2bf(src[(size_t)e * 256]);
}

// pack w1: g = ((l*8 + nt)*8 + ks) ; d = nt*16+al, ch = ks*32+ah*8+e
__global__ __launch_bounds__(256) void pack1_kernel(const float* __restrict__ w1,
                                                    unsigned short* __restrict__ w1f) {
    int g = blockIdx.x * 4 + (threadIdx.x >> 6);
    int lane = threadIdx.x & 63;
    int ks = g & 7;
    int nt = (g >> 3) & 7;
    int l = g >> 6;
    int al = lane & 15, ah = lane >> 4;
    int d = nt * 16 + al;
    int c0 = ks * 32 + ah * 8;
    const float* src = w1 + ((size_t)l * 256 + c0) * 128 + d;
    unsigned short* dst = w1f + ((size_t)g * 64 + lane) * 8;
#pragma unroll
    for (int e = 0; e < 8; ++e)
        dst[e] = f2bf(src[(size_t)e * 128]);
}

// ---------------------------------------------------------------------------
__global__ __launch_bounds__(256) void ln_kernel(const float* __restrict__ Y,
                                                 const float* __restrict__ scale,
                                                 const float* __restrict__ bias,
                                                 unsigned short* __restrict__ Yn) {
    int wave = threadIdx.x >> 6;
    int lane = threadIdx.x & 63;
    int r = blockIdx.x * 4 + wave;
    const float* yr = Y + (size_t)r * DDc;
    float2 v = *(const float2*)(yr + lane * 2);
    float s = v.x + v.y;
#pragma unroll
    for (int off = 32; off >= 1; off >>= 1) s += __shfl_xor(s, off, 64);
    float mean = s * (1.0f / 128.0f);
    float dx = v.x - mean, dy = v.y - mean;
    float s2 = dx * dx + dy * dy;
#pragma unroll
    for (int off = 32; off >= 1; off >>= 1) s2 += __shfl_xor(s2, off, 64);
    float rstd = rsqrtf(s2 * (1.0f / 128.0f) + 1e-5f);
    float2 sc = *(const float2*)(scale + lane * 2);
    float2 bi = *(const float2*)(bias + lane * 2);
    ushort2 o;
    o.x = f2bf(dx * rstd * sc.x + bi.x);
    o.y = f2bf(dy * rstd * sc.y + bi.y);
    *(ushort2*)(Yn + (size_t)r * DDc + lane * 2) = o;
}

// ---------------------------------------------------------------------------
// Fused MFMA layer kernel. Block = (b, row-pair), 256 threads = 4 waves.
// LDS: A-slab (28672 B) ALIASED with H (32768 B), + 256 B zero pad.
// Conv MFMAs operand-SWAPPED: acc = mfma(Wfrag, Actfrag).
// Weights are pre-packed in fragment order -> every B-frag load is a
// contiguous 1KB wave-load (base + lane*16B). Depth-1 pipeline pinned by
// sched_barrier(0); no barrier inside the K-loop so waitcnts stay counted.
#define Z_OFF 32768
#define LDS_TOTAL 33024

__global__ __launch_bounds__(256, 3) void conv_mfma_kernel(
    const unsigned short* __restrict__ Yn,
    const unsigned short* __restrict__ w3f,    // fragment-packed, per layer
    const float* __restrict__ b3l,
    const unsigned short* __restrict__ w1f,    // fragment-packed, per layer
    const float* __restrict__ b1l,
    float* __restrict__ Y) {
    __shared__ __align__(16) char lds[LDS_TOTAL];

    int bx = blockIdx.x;
    int b = bx / 13;
    int h0 = (bx - b * 13) * 2;
    int tid = threadIdx.x;
    int lane = tid & 63, wv = tid >> 6;
    int al = lane & 15, ah = lane >> 4;

    // ---- stage A: rows h0-1..h0+2, cols -1..26, 128ch bf16, XOR-swizzled rows
    for (int i = tid; i < 4 * 28 * 16; i += 256) {     // 16B chunks
        int row4 = i / (28 * 16);
        int rem = i - row4 * (28 * 16);
        int col = rem >> 4;
        int c8 = (rem & 15) << 3;
        int hs = h0 - 1 + row4;
        int ws = col - 1;
        uint4 v = make_uint4(0u, 0u, 0u, 0u);
        if (hs >= 0 && hs < Hh && ws >= 0 && ws < Ww)
            v = *(const uint4*)(Yn + (((size_t)(b * Hh + hs) * Ww + ws) << 7) + c8);
        int r = row4 * 28 + col;
        unsigned int addr = (unsigned int)(r * 256 + c8 * 2);
        addr ^= (unsigned int)((r & 7) << 4);
        *(uint4*)(lds + addr) = v;
    }
    if (tid < 16) *(uint4*)(lds + Z_OFF + tid * 16) = make_uint4(0u, 0u, 0u, 0u);
    __syncthreads();

    // ---- per-lane M decomposition (m = mt*16 + al)
    int r00[4]; bool mpad[4];
#pragma unroll
    for (int mt = 0; mt < 4; ++mt) {
        int m = mt * 16 + al;
        bool pad = (m >= 52);
        int rh = (m >= 26) ? 1 : 0;
        int w = m - rh * 26;
        if (pad) { rh = 1; w = 0; }
        mpad[mt] = pad;
        r00[mt] = rh * 28 + w;
    }

    // ---- conv 3x3 via swapped MFMA, software-pipelined depth 1 (pinned)
    f32x4 acc[4][4];
#pragma unroll
    for (int mt = 0; mt < 4; ++mt)
#pragma unroll
        for (int nt = 0; nt < 4; ++nt) acc[mt][nt] = (f32x4)0.0f;

    int nw0 = wv * 64;
    // fragment-packed base: wave wv owns chunks [wv*16 .. wv*16+15] of each tap
    const unsigned short* pB = w3f + wv * 8192 + lane * 8;
    const unsigned short* pBt = pB;

    unsigned int ah16 = (unsigned int)(ah * 16);
    unsigned int abase[4];
#pragma unroll
    for (int mt = 0; mt < 4; ++mt) {
        int row = r00[mt];                        // tap 0: dh=0,dw=0
        unsigned int sw = (unsigned int)((row & 7) << 4);
        abase[mt] = mpad[mt] ? (unsigned int)(Z_OFF) + ah16
                             : ((unsigned int)(row << 8) + (ah16 ^ sw));
    }

    short8v bc[4], afc[4];
#pragma unroll
    for (int nt = 0; nt < 4; ++nt) bc[nt] = *(const short8v*)(pBt + nt * 2048);
#pragma unroll
    for (int mt = 0; mt < 4; ++mt) afc[mt] = *(const short8v*)(lds + abase[mt]);

    int dh = 0, dw = 0;
#pragma unroll 1
    for (int tap = 0; tap < 9; ++tap) {
        // next tap's A row bases
        int dwn = dw + 1, dhn = dh;
        if (dwn == 3) { dwn = 0; dhn += 1; }
        unsigned int abasen[4];
#pragma unroll
        for (int mt = 0; mt < 4; ++mt) {
            int row = r00[mt] + dhn * 28 + dwn;
            if (row > 111) row = 111;             // tap==8 dummy prefetch clamp
            unsigned int sw = (unsigned int)((row & 7) << 4);
            abasen[mt] = mpad[mt] ? (unsigned int)(Z_OFF) + ah16
                                  : ((unsigned int)(row << 8) + (ah16 ^ sw));
        }
#pragma unroll
        for (int ks = 0; ks < 4; ++ks) {
            short8v bn[4], afn[4];
            const unsigned short* pn = (ks < 3) ? (pBt + (ks + 1) * 512) : (pBt + 32768);
#pragma unroll
            for (int nt = 0; nt < 4; ++nt) bn[nt] = *(const short8v*)(pn + nt * 2048);
#pragma unroll
            for (int mt = 0; mt < 4; ++mt) {
                unsigned int a = (ks < 3) ? (abase[mt] ^ (unsigned int)((ks + 1) << 6))
                                          : abasen[mt];
                afn[mt] = *(const short8v*)(lds + a);
            }
            // Pin: next-step loads must issue BEFORE this step's MFMA cluster.
            __builtin_amdgcn_sched_barrier(0);
#pragma unroll
            for (int mt = 0; mt < 4; ++mt)
#pragma unroll
                for (int nt = 0; nt < 4; ++nt)
                    acc[mt][nt] = __builtin_amdgcn_mfma_f32_16x16x32_bf16(
                        bc[nt], afc[mt], acc[mt][nt], 0, 0, 0);
#pragma unroll
            for (int nt = 0; nt < 4; ++nt) bc[nt] = bn[nt];
#pragma unroll
            for (int mt = 0; mt < 4; ++mt) afc[mt] = afn[mt];
        }
#pragma unroll
        for (int mt = 0; mt < 4; ++mt) abase[mt] = abasen[mt];
        pBt += 32768;
        dw = dwn; dh = dhn;
    }
    __syncthreads();   // all A-reads done; H region may now overwrite A region

    // ---- bias + gelu -> H [64 m][256 n] bf16, packed b64 writes
    unsigned int hswz = ((unsigned int)(al & 7)) << 4;   // m&7 == al&7
#pragma unroll
    for (int nt = 0; nt < 4; ++nt) {
        int n0 = nw0 + nt * 16 + ah * 4;
        float4 bv = *(const float4*)(b3l + n0);
#pragma unroll
        for (int mt = 0; mt < 4; ++mt) {
            int m = mt * 16 + al;
            ushort4v o;
            o[0] = f2bf(fast_gelu(acc[mt][nt][0] + bv.x));
            o[1] = f2bf(fast_gelu(acc[mt][nt][1] + bv.y));
            o[2] = f2bf(fast_gelu(acc[mt][nt][2] + bv.z));
            o[3] = f2bf(fast_gelu(acc[mt][nt][3] + bv.w));
            unsigned int addr = ((unsigned int)(m * 512 + n0 * 2)) ^ hswz;
            *(ushort4v*)(lds + addr) = o;
        }
    }
    __syncthreads();

    // ---- 1x1 via MFMA: [64 x 256] @ [256 -> 128]
    f32x4 acc1[4][2];
#pragma unroll
    for (int mt = 0; mt < 4; ++mt) { acc1[mt][0] = (f32x4)0.0f; acc1[mt][1] = (f32x4)0.0f; }
    const unsigned short* pW1 = w1f + wv * 8192 + lane * 8;
    int nw1 = wv * 32;

#pragma unroll
    for (int ks = 0; ks < 8; ++ks) {
        short8v hf[4], wf[2];
#pragma unroll
        for (int mt = 0; mt < 4; ++mt) {
            unsigned int a = ((unsigned int)((mt * 16 + al) * 512 + ks * 64 + ah * 16)) ^ hswz;
            hf[mt] = *(const short8v*)(lds + a);
        }
        wf[0] = *(const short8v*)(pW1 + ks * 512);
        wf[1] = *(const short8v*)(pW1 + 4096 + ks * 512);
#pragma unroll
        for (int mt = 0; mt < 4; ++mt)
#pragma unroll
            for (int ntl = 0; ntl < 2; ++ntl)
                acc1[mt][ntl] = __builtin_amdgcn_mfma_f32_16x16x32_bf16(
                    hf[mt], wf[ntl], acc1[mt][ntl], 0, 0, 0);
    }

    // ---- bias + residual into Y (fp32)
#pragma unroll
    for (int ntl = 0; ntl < 2; ++ntl) {
        int n = nw1 + ntl * 16 + al;
        float bias = b1l[n];
#pragma unroll
        for (int mt = 0; mt < 4; ++mt) {
#pragma unroll
            for (int j = 0; j < 4; ++j) {
                int m = mt * 16 + ah * 4 + j;
                if (m < 52) {
                    int rh = (m >= 26) ? 1 : 0;
                    int w = m - rh * 26;
                    float* yp = Y + (((size_t)(b * Hh + h0 + rh) * Ww + w) << 7) + n;
                    *yp += acc1[mt][ntl][j] + bias;
                }
            }
        }
    }
}

// ---------------------------------------------------------------------------
__global__ __launch_bounds__(256) void gather_kernel(const float* __restrict__ Y,
                                                     const int* __restrict__ coords,
                                                     float* __restrict__ Z) {
    int idx = blockIdx.x * blockDim.x + threadIdx.x;
    int r = idx >> 5;
    int c4 = idx & 31;
    int b = r / Ll;
    int li = r - b * Ll;
    int row = coords[2 * li + 0];
    int col = coords[2 * li + 1];
    float4 v = *(const float4*)(Y + (((size_t)(b * NPIX + row * Ww + col)) * DDc + c4 * 4));
    *(float4*)(Z + ((size_t)r * DDc + c4 * 4)) = v;
}

// ---------------------------------------------------------------------------
extern "C" void kernel_launch(void* const* d_in, const int* in_sizes, int n_in,
                              void* d_out, int out_size, void* d_ws, size_t ws_size,
                              hipStream_t stream) {
    const float* X = (const float*)d_in[0];
    const int* coords = (const int*)d_in[1];
    const float* P = (const float*)d_in[2];
    const float* ln_scale = (const float*)d_in[3];
    const float* ln_bias = (const float*)d_in[4];
    const float* w3 = (const float*)d_in[5];
    const float* b3 = (const float*)d_in[6];
    const float* w1 = (const float*)d_in[7];
    const float* b1 = (const float*)d_in[8];

    float* Y = (float*)d_ws;
    unsigned short* Yn = (unsigned short*)(Y + GRID_ELEMS);
    unsigned short* w3f = Yn + GRID_ELEMS;                       // 4*9*32768
    unsigned short* w1f = w3f + (size_t)NLl * 9 * CHc * DDc;     // 4*32768
    int* inv = (int*)(w1f + (size_t)NLl * DDc * CHc);

    build_inv_kernel<<<1, 1024, 0, stream>>>(coords, inv);

    pack3_kernel<<<(NLl * 9 * 16 * 4) / 4, 256, 0, stream>>>(w3, w3f);
    pack1_kernel<<<(NLl * 8 * 8) / 4, 256, 0, stream>>>(w1, w1f);

    scatter_kernel<<<(NROWS * 32) / 256, 256, 0, stream>>>(X, P, inv, Y);

    for (int l = 0; l < NLl; ++l) {
        ln_kernel<<<NROWS / 4, 256, 0, stream>>>(Y, ln_scale + l * DDc, ln_bias + l * DDc, Yn);
        conv_mfma_kernel<<<Bsz * 13, 256, 0, stream>>>(
            Yn,
            w3f + (size_t)l * 9 * CHc * DDc,
            b3 + (size_t)l * CHc,
            w1f + (size_t)l * DDc * CHc,
            b1 + (size_t)l * DDc,
            Y);
    }

    gather_kernel<<<(Bsz * Ll * 32) / 256, 256, 0, stream>>>(Y, coords, (float*)d_out);
}